// Round 17
// baseline (158.505 us; speedup 1.0000x reference)
//
#include <hip/hip_runtime.h>
#include <stdint.h>

#define B_ 2
#define S_ 2048
#define D_ 1024
#define H_ 16
#define DK_ 64

typedef __attribute__((ext_vector_type(8))) short short8;   // 8 x bf16 (raw bits)
typedef __attribute__((ext_vector_type(4))) float f32x4;

__device__ __forceinline__ short f2bf(float f) {
    uint32_t u = __float_as_uint(f);
    return (short)((u + 0x7FFFu + ((u >> 16) & 1u)) >> 16);
}

__device__ __forceinline__ float fexp2(float x) {
    float r;
    asm("v_exp_f32 %0, %1" : "=v"(r) : "v"(x));
    return r;
}

__device__ __forceinline__ uint32_t cvt_pk_bf16(float lo, float hi) {
    uint32_t r;
    asm("v_cvt_pk_bf16_f32 %0, %1, %2" : "=v"(r) : "v"(lo), "v"(hi));
    return r;
}

#define GLOAD16(gptr, lptr)                                                      \
    __builtin_amdgcn_global_load_lds(                                            \
        (const __attribute__((address_space(1))) void*)(gptr),                   \
        (__attribute__((address_space(3))) void*)(lptr), 16, 0, 0)

// ---------------- fused prep: casts + mask pack + LUT (R14 proven) ----------------
__global__ __launch_bounds__(256) void prep(const float* __restrict__ q,
                                            const float* __restrict__ k,
                                            const float* __restrict__ v,
                                            const float* __restrict__ wq,
                                            const float* __restrict__ wk,
                                            const float* __restrict__ wv,
                                            const float* __restrict__ wo,
                                            const int* __restrict__ mask,
                                            short* __restrict__ qb, short* __restrict__ kb,
                                            short* __restrict__ vb,
                                            short* __restrict__ wqb, short* __restrict__ wkb,
                                            short* __restrict__ wvb, short* __restrict__ wob,
                                            uint32_t* __restrict__ packed,
                                            float* __restrict__ lut) {
    int bid = blockIdx.x;
    int tid = threadIdx.x;
    if (bid < 8192) {
        const float* in;
        short* out;
        int i;
        if (bid < 6144) {
            int sel = bid >> 11;
            i = (bid & 2047) * 256 + tid;
            in = (sel == 0) ? q : (sel == 1) ? k : v;
            out = (sel == 0) ? qb : (sel == 1) ? kb : vb;
        } else {
            int idx = bid - 6144;
            int sel = idx >> 9;
            i = (idx & 511) * 256 + tid;
            in = (sel == 0) ? wq : (sel == 1) ? wk : (sel == 2) ? wv : wo;
            out = (sel == 0) ? wqb : (sel == 1) ? wkb : (sel == 2) ? wvb : wob;
            if (idx == 0 && tid < 64) {
                int e = tid >> 2, r = tid & 3;
                lut[tid] = ((e >> r) & 1) ? 0.0f : -8.0e9f;   // raw-score bias (x0.125 => -1e9)
            }
        }
        const float4* p = ((const float4*)in) + (size_t)i * 2;
        float4 x = p[0], y = p[1];
        short8 o;
        o[0] = f2bf(x.x); o[1] = f2bf(x.y); o[2] = f2bf(x.z); o[3] = f2bf(x.w);
        o[4] = f2bf(y.x); o[5] = f2bf(y.y); o[6] = f2bf(y.z); o[7] = f2bf(y.w);
        *(((short8*)out) + i) = o;
    } else {
        size_t t = (size_t)(bid - 8192) * 256 + tid;   // covers 4 mask elems
        int4 m = ((const int4*)mask)[t];
        uint32_t nib = (m.x != 0 ? 1u : 0u) | (m.y != 0 ? 2u : 0u) |
                       (m.z != 0 ? 4u : 0u) | (m.w != 0 ? 8u : 0u);
        int lane = tid & 63;
        uint32_t vv = nib << ((lane & 7) * 4);
        vv |= __shfl_xor(vv, 1);
        vv |= __shfl_xor(vv, 2);
        vv |= __shfl_xor(vv, 4);
        if ((lane & 7) == 0) packed[t >> 3] = vv;
    }
}

// ---------------- GEMM core (no epilogue): 128x128 tile, BK=32, XCD-chunked swizzle ----------------
#define GEMM_CORE(A, W, Kv)                                                                 \
    __shared__ short As[128 * 32];                                                          \
    __shared__ short Bs[128 * 32];                                                          \
    const int tid = threadIdx.x;                                                            \
    const int lane = tid & 63;                                                              \
    const int w = tid >> 6;                                                                 \
    const int wm = w >> 1, wn = w & 1;                                                      \
    const int l_ = blockIdx.x + (blockIdx.y << 3);                                          \
    const int xcd_ = l_ & 7, ii_ = l_ >> 3;                                                 \
    const int mBase = ((xcd_ << 2) + (ii_ >> 3)) * 128;                                     \
    const int nBase = (ii_ & 7) * 128;                                                      \
    f32x4 acc[4][4];                                                                        \
    _Pragma("unroll") for (int i = 0; i < 4; i++)                                           \
        _Pragma("unroll") for (int j = 0; j < 4; j++) acc[i][j] = (f32x4)0.f;               \
    const int srow = lane >> 2;                                                             \
    const int sslot = lane & 3;                                                             \
    for (int k0 = 0; k0 < Kv; k0 += 32) {                                                   \
        _Pragma("unroll") for (int i = 0; i < 2; ++i) {                                     \
            int seg = w * 2 + i;                                                            \
            int row = seg * 16 + srow;                                                      \
            const short* ga = A + (size_t)(mBase + row) * Kv + k0 + sslot * 8;              \
            GLOAD16(ga, (char*)As + seg * 1024);                                            \
            const short* gb = W + (size_t)(nBase + row) * Kv + k0 + sslot * 8;              \
            GLOAD16(gb, (char*)Bs + seg * 1024);                                            \
        }                                                                                   \
        asm volatile("s_waitcnt vmcnt(0)" ::: "memory");                                    \
        __syncthreads();                                                                    \
        short8 af[4], bfv[4];                                                               \
        _Pragma("unroll") for (int mi = 0; mi < 4; mi++)                                    \
            af[mi] = *(const short8*)&As[(wm * 64 + mi * 16 + (lane & 15)) * 32 + (lane >> 4) * 8]; \
        _Pragma("unroll") for (int ni = 0; ni < 4; ni++)                                    \
            bfv[ni] = *(const short8*)&Bs[(wn * 64 + ni * 16 + (lane & 15)) * 32 + (lane >> 4) * 8]; \
        _Pragma("unroll") for (int mi = 0; mi < 4; mi++)                                    \
            _Pragma("unroll") for (int ni = 0; ni < 4; ni++)                                \
                acc[mi][ni] = __builtin_amdgcn_mfma_f32_16x16x32_bf16(af[mi], bfv[ni], acc[mi][ni], 0, 0, 0); \
        __syncthreads();                                                                    \
    }

// z=0,1: Q/K projections (row-major bf16 out); z=2: V projection with FUSED transpose
// epilogue writing Vt[((b*16+h)*64+dk)*S + s] directly (packed 8B stores).
__global__ __launch_bounds__(256) void gemm3_nt(const short* __restrict__ A0, const short* __restrict__ W0, short* __restrict__ C0,
                                                const short* __restrict__ A1, const short* __restrict__ W1, short* __restrict__ C1,
                                                const short* __restrict__ A2, const short* __restrict__ W2, short* __restrict__ Vt) {
    const int z = blockIdx.z;
    const short* A = (z == 0) ? A0 : (z == 1) ? A1 : A2;
    const short* W = (z == 0) ? W0 : (z == 1) ? W1 : W2;
    GEMM_CORE(A, W, D_)
    if (z == 2) {
        // transposed epilogue: 4 consecutive s at fixed dk -> one uint2 store
#pragma unroll
        for (int mi = 0; mi < 4; mi++)
#pragma unroll
            for (int ni = 0; ni < 4; ni++) {
                int row = mBase + wm * 64 + mi * 16 + (lane >> 4) * 4;   // global s base
                int col = nBase + wn * 64 + ni * 16 + (lane & 15);       // d index
                int bq = row >> 11, sl2 = row & 2047;
                size_t vtrow = (size_t)((bq * 16 + (col >> 6)) * 64 + (col & 63));
                uint2 o;
                o.x = cvt_pk_bf16(acc[mi][ni][0], acc[mi][ni][1]);
                o.y = cvt_pk_bf16(acc[mi][ni][2], acc[mi][ni][3]);
                *(uint2*)&Vt[vtrow * S_ + sl2] = o;
            }
    } else {
        short* C = (z == 0) ? C0 : C1;
#pragma unroll
        for (int mi = 0; mi < 4; mi++)
#pragma unroll
            for (int ni = 0; ni < 4; ni++)
#pragma unroll
                for (int r = 0; r < 4; r++) {
                    int row = mBase + wm * 64 + mi * 16 + (lane >> 4) * 4 + r;
                    int col = nBase + wn * 64 + ni * 16 + (lane & 15);
                    C[(size_t)row * D_ + col] = f2bf(acc[mi][ni][r]);
                }
    }
}

// ---------------- gemm_out: 64x128 tile, grid (8,64) = 512 blocks = 2 blk/CU (R14 proven) ----------------
__global__ __launch_bounds__(256) void gemm_out(const short* __restrict__ A,
                                                const short* __restrict__ W,
                                                float* __restrict__ C) {
    __shared__ short As[64 * 32];     // 4 KB
    __shared__ short Bs[128 * 32];    // 8 KB
    const int tid = threadIdx.x;
    const int lane = tid & 63;
    const int w = tid >> 6;
    const int wm = w >> 1, wn = w & 1;
    const int li = lane & 15, lg = lane >> 4;
    const int l_ = blockIdx.x + (blockIdx.y << 3);
    const int xcd_ = l_ & 7, ii_ = l_ >> 3;           // ii_ in [0,64)
    const int mBase = ((xcd_ << 3) + (ii_ >> 3)) * 64;  // 64 m-tiles of 64 rows
    const int nBase = (ii_ & 7) * 128;
    const int Kv = D_, Nv = D_;
    f32x4 acc[2][4];
#pragma unroll
    for (int i = 0; i < 2; i++)
#pragma unroll
        for (int j = 0; j < 4; j++) acc[i][j] = (f32x4)0.f;
    const int srow = lane >> 2;       // 0..15 within 16-row segment
    const int sslot = lane & 3;
    for (int k0 = 0; k0 < Kv; k0 += 32) {
        {   // A: 4 segments, one per wave (64 rows total)
            int row = w * 16 + srow;
            const short* ga = A + (size_t)(mBase + row) * Kv + k0 + sslot * 8;
            GLOAD16(ga, (char*)As + w * 1024);
        }
#pragma unroll
        for (int i = 0; i < 2; ++i) {   // B: 8 segments, two per wave
            int seg = w * 2 + i;
            int row = seg * 16 + srow;
            const short* gb = W + (size_t)(nBase + row) * Kv + k0 + sslot * 8;
            GLOAD16(gb, (char*)Bs + seg * 1024);
        }
        asm volatile("s_waitcnt vmcnt(0)" ::: "memory");
        __syncthreads();
        short8 af[2], bfv[4];
#pragma unroll
        for (int mi = 0; mi < 2; mi++)
            af[mi] = *(const short8*)&As[(wm * 32 + mi * 16 + li) * 32 + lg * 8];
#pragma unroll
        for (int ni = 0; ni < 4; ni++)
            bfv[ni] = *(const short8*)&Bs[(wn * 64 + ni * 16 + li) * 32 + lg * 8];
#pragma unroll
        for (int mi = 0; mi < 2; mi++)
#pragma unroll
            for (int ni = 0; ni < 4; ni++)
                acc[mi][ni] = __builtin_amdgcn_mfma_f32_16x16x32_bf16(af[mi], bfv[ni], acc[mi][ni], 0, 0, 0);
        __syncthreads();
    }
#pragma unroll
    for (int mi = 0; mi < 2; mi++)
#pragma unroll
        for (int ni = 0; ni < 4; ni++)
#pragma unroll
            for (int r = 0; r < 4; r++) {
                int row = mBase + wm * 32 + mi * 16 + lg * 4 + r;
                int col = nBase + wn * 64 + ni * 16 + li;
                C[(size_t)row * Nv + col] = acc[mi][ni][r];
            }
}

// ---------------- flash attention: QBLK=128, 4 waves x 32 q-rows (dual q-set), KVBLK=128 ----------------
// R11-proven body: defer-max + deferred l-sum. grid (16,32) swizzled, 256 threads.
__global__ __launch_bounds__(256) void attn_kernel(const short* __restrict__ Qp,
                                                   const short* __restrict__ Kp,
                                                   const short* __restrict__ Vt,
                                                   const uint32_t* __restrict__ mp,
                                                   const float* __restrict__ lutg,
                                                   short* __restrict__ Op) {
    __shared__ short Ks[2][2][64 * 64];   // [dbuf][sub-tile][row*64+col] = 32 KB
    __shared__ short Vs[2][2][64 * 64];   // 32 KB
    // XCD-chunked: each XCD owns 4 consecutive bh
    const int l_ = blockIdx.x + (blockIdx.y << 4);
    const int bh = ((l_ & 7) << 2) + (l_ >> 7);
    const int qt = (l_ >> 3) & 15;
    const int b = bh >> 4, h = bh & 15;
    const int qBase = qt * 128;
    const int tid = threadIdx.x, lane = tid & 63, w = tid >> 6;
    const int lg = lane >> 4;
    const int li = lane & 15;
    const float c1 = 0.18033688011112042f;   // 0.125 * log2(e)

    const int qA = qBase + w * 32 + li;       // set A q-row
    const int qB = qA + 16;                   // set B q-row

    short8 qfA[2], qfB[2];
#pragma unroll
    for (int ks = 0; ks < 2; ks++) {
        qfA[ks] = *(const short8*)&Qp[(size_t)(b * S_ + qA) * D_ + h * 64 + lg * 8 + ks * 32];
        qfB[ks] = *(const short8*)&Qp[(size_t)(b * S_ + qB) * D_ + h * 64 + lg * 8 + ks * 32];
    }

    // staging (256 threads): per 8KB subtile, two lines (rows r0, r0+32)
    const int r0 = tid >> 3, sl = tid & 7;
    const int gs = sl ^ (r0 & 7);
    const short* kgb = Kp + ((size_t)(b * S_) + r0) * D_ + h * 64 + gs * 8;   // + krow*D
    const short* vgb = Vt + ((size_t)bh * 64 + r0) * S_ + gs * 8;             // + kcol
    const uint32_t* mrowA = mp + ((size_t)(b * S_) + qA) * 64;
    const uint32_t* mrowB = mp + ((size_t)(b * S_) + qB) * 64;
    char* ldsK = (char*)&Ks[0][0][0];
    char* ldsV = (char*)&Vs[0][0][0];
    const int woff = w * 1024;

    // prologue: stage pair 0 into buffer 0
#pragma unroll
    for (int st = 0; st < 2; st++) {
        GLOAD16(kgb + (size_t)(st * 64) * D_, ldsK + st * 8192 + woff);
        GLOAD16(kgb + (size_t)(st * 64 + 32) * D_, ldsK + st * 8192 + 4096 + woff);
        GLOAD16(vgb + st * 64, ldsV + st * 8192 + woff);
        GLOAD16(vgb + st * 64 + (size_t)32 * S_, ldsV + st * 8192 + 4096 + woff);
    }
    uint4 mw4a = *(const uint4*)mrowA;
    uint4 mw4b = *(const uint4*)mrowB;
    asm volatile("s_waitcnt vmcnt(0)" ::: "memory");
    __syncthreads();

    float m_rA = -1e30f, l_rA = 0.f, m_rB = -1e30f, l_rB = 0.f;
    f32x4 accA[4], accB[4];
#pragma unroll
    for (int g = 0; g < 4; g++) { accA[g] = (f32x4)0.f; accB[g] = (f32x4)0.f; }

    int cur = 0;

    for (int kt = 0; kt < S_ / 128; ++kt) {
        // mask bias LUT loads FIRST
        uint32_t mwaA[4] = {mw4a.x, mw4a.y, mw4a.z, mw4a.w};
        uint32_t mwaB[4] = {mw4b.x, mw4b.y, mw4b.z, mw4b.w};
        f32x4 mskA[8], mskB[8];
#pragma unroll
        for (int nt = 0; nt < 8; nt++) {
            uint32_t sh = ((nt & 1) << 4) + (lg << 2);
            mskA[nt] = *(const f32x4*)&lutg[((mwaA[nt >> 1] >> sh) & 0xFu) * 4];
            mskB[nt] = *(const f32x4*)&lutg[((mwaB[nt >> 1] >> sh) & 0xFu) * 4];
        }

        uint4 mwnA, mwnB;
        if (kt < S_ / 128 - 1) {   // async prefetch of next 128-tile
            const int boff = (cur ^ 1) * 16384 + woff;
#pragma unroll
            for (int st = 0; st < 2; st++) {
                const size_t kr = (size_t)((kt + 1) * 128 + st * 64);
                GLOAD16(kgb + kr * D_, ldsK + boff + st * 8192);
                GLOAD16(kgb + (kr + 32) * D_, ldsK + boff + st * 8192 + 4096);
                GLOAD16(vgb + kr, ldsV + boff + st * 8192);
                GLOAD16(vgb + kr + (size_t)32 * S_, ldsV + boff + st * 8192 + 4096);
            }
            mwnA = *(const uint4*)&mrowA[(kt + 1) * 4];
            mwnB = *(const uint4*)&mrowB[(kt + 1) * 4];
        }

        // S^T = K Q^T + mask_bias: each kf read feeds BOTH q-sets
        f32x4 scA[8], scB[8];
        __builtin_amdgcn_s_setprio(1);
#pragma unroll
        for (int st = 0; st < 2; st++)
#pragma unroll
            for (int ntl = 0; ntl < 4; ntl++) {
                f32x4 cA = mskA[st * 4 + ntl];
                f32x4 cB = mskB[st * 4 + ntl];
#pragma unroll
                for (int ks = 0; ks < 2; ks++) {
                    short8 kf = *(const short8*)&Ks[cur][st][(ntl * 16 + li) * 64 + (((lg + ks * 4) ^ (li & 7)) << 3)];
                    cA = __builtin_amdgcn_mfma_f32_16x16x32_bf16(kf, qfA[ks], cA, 0, 0, 0);
                    cB = __builtin_amdgcn_mfma_f32_16x16x32_bf16(kf, qfB[ks], cB, 0, 0, 0);
                }
                scA[st * 4 + ntl] = cA;
                scB[st * 4 + ntl] = cB;
            }
        __builtin_amdgcn_s_setprio(0);

        // row max per set (balanced trees + 2 shfl each)
        float a0 = fmaxf(fmaxf(scA[0][0], scA[0][1]), fmaxf(scA[0][2], scA[0][3]));
        float a1 = fmaxf(fmaxf(scA[1][0], scA[1][1]), fmaxf(scA[1][2], scA[1][3]));
        float a2 = fmaxf(fmaxf(scA[2][0], scA[2][1]), fmaxf(scA[2][2], scA[2][3]));
        float a3 = fmaxf(fmaxf(scA[3][0], scA[3][1]), fmaxf(scA[3][2], scA[3][3]));
        float a4 = fmaxf(fmaxf(scA[4][0], scA[4][1]), fmaxf(scA[4][2], scA[4][3]));
        float a5 = fmaxf(fmaxf(scA[5][0], scA[5][1]), fmaxf(scA[5][2], scA[5][3]));
        float a6 = fmaxf(fmaxf(scA[6][0], scA[6][1]), fmaxf(scA[6][2], scA[6][3]));
        float a7 = fmaxf(fmaxf(scA[7][0], scA[7][1]), fmaxf(scA[7][2], scA[7][3]));
        float tmA = fmaxf(fmaxf(fmaxf(a0, a1), fmaxf(a2, a3)),
                          fmaxf(fmaxf(a4, a5), fmaxf(a6, a7)));
        tmA = fmaxf(tmA, __shfl_xor(tmA, 16));
        tmA = fmaxf(tmA, __shfl_xor(tmA, 32));
        float b0 = fmaxf(fmaxf(scB[0][0], scB[0][1]), fmaxf(scB[0][2], scB[0][3]));
        float b1 = fmaxf(fmaxf(scB[1][0], scB[1][1]), fmaxf(scB[1][2], scB[1][3]));
        float b2 = fmaxf(fmaxf(scB[2][0], scB[2][1]), fmaxf(scB[2][2], scB[2][3]));
        float b3 = fmaxf(fmaxf(scB[3][0], scB[3][1]), fmaxf(scB[3][2], scB[3][3]));
        float b4 = fmaxf(fmaxf(scB[4][0], scB[4][1]), fmaxf(scB[4][2], scB[4][3]));
        float b5 = fmaxf(fmaxf(scB[5][0], scB[5][1]), fmaxf(scB[5][2], scB[5][3]));
        float b6 = fmaxf(fmaxf(scB[6][0], scB[6][1]), fmaxf(scB[6][2], scB[6][3]));
        float b7 = fmaxf(fmaxf(scB[7][0], scB[7][1]), fmaxf(scB[7][2], scB[7][3]));
        float tmB = fmaxf(fmaxf(fmaxf(b0, b1), fmaxf(b2, b3)),
                          fmaxf(fmaxf(b4, b5), fmaxf(b6, b7)));
        tmB = fmaxf(tmB, __shfl_xor(tmB, 16));
        tmB = fmaxf(tmB, __shfl_xor(tmB, 32));

        // combined defer-max (rescale both sets when either grows)
        if (__any(((tmA - m_rA) * c1 > 10.0f) || ((tmB - m_rB) * c1 > 10.0f))) {
            float mnA = fmaxf(m_rA, tmA);
            float alA = fexp2((m_rA - mnA) * c1);
            m_rA = mnA; l_rA *= alA;
            float mnB = fmaxf(m_rB, tmB);
            float alB = fexp2((m_rB - mnB) * c1);
            m_rB = mnB; l_rB *= alB;
#pragma unroll
            for (int g = 0; g < 4; g++) { accA[g] *= alA; accB[g] *= alB; }
        }
        float mcA = m_rA * c1, mcB = m_rB * c1;

        // p = exp2(s*c1 - mc); pack bf16 pairs (per set); l-sum kept per-lane (deferred reduce)
        uint32_t uA[8][2], uB[8][2];
        float lsA = 0.f, lsB = 0.f;
#pragma unroll
        for (int nt = 0; nt < 8; nt++) {
            float e0 = fexp2(__builtin_fmaf(scA[nt][0], c1, -mcA));
            float e1 = fexp2(__builtin_fmaf(scA[nt][1], c1, -mcA));
            float e2 = fexp2(__builtin_fmaf(scA[nt][2], c1, -mcA));
            float e3 = fexp2(__builtin_fmaf(scA[nt][3], c1, -mcA));
            lsA += (e0 + e1) + (e2 + e3);
            uA[nt][0] = cvt_pk_bf16(e0, e1);
            uA[nt][1] = cvt_pk_bf16(e2, e3);
            float f0 = fexp2(__builtin_fmaf(scB[nt][0], c1, -mcB));
            float f1 = fexp2(__builtin_fmaf(scB[nt][1], c1, -mcB));
            float f2 = fexp2(__builtin_fmaf(scB[nt][2], c1, -mcB));
            float f3 = fexp2(__builtin_fmaf(scB[nt][3], c1, -mcB));
            lsB += (f0 + f1) + (f2 + f3);
            uB[nt][0] = cvt_pk_bf16(f0, f1);
            uB[nt][1] = cvt_pk_bf16(f2, f3);
        }
        l_rA += lsA;    // per-lane partial; cross-lane reduce deferred to epilogue
        l_rB += lsB;

        // O^T += V^T P^T; each vf read feeds BOTH q-sets; P redistribution via xor-16
        __builtin_amdgcn_s_setprio(1);
#pragma unroll
        for (int ks = 0; ks < 4; ks++) {
            const uint32_t sA00 = uA[2 * ks][0], sA01 = uA[2 * ks][1];
            const uint32_t sA10 = uA[2 * ks + 1][0], sA11 = uA[2 * ks + 1][1];
            uint32_t eA0 = (lg & 1) ? sA00 : sA10;
            uint32_t eA1 = (lg & 1) ? sA01 : sA11;
            uint32_t xA0 = (uint32_t)__shfl_xor((int)eA0, 16);
            uint32_t xA1 = (uint32_t)__shfl_xor((int)eA1, 16);
            union { uint32_t w4[4]; short8 s8; } puA;
            puA.w4[0] = (lg & 1) ? xA0 : sA00;
            puA.w4[1] = (lg & 1) ? xA1 : sA01;
            puA.w4[2] = (lg & 1) ? sA10 : xA0;
            puA.w4[3] = (lg & 1) ? sA11 : xA1;
            const uint32_t sB00 = uB[2 * ks][0], sB01 = uB[2 * ks][1];
            const uint32_t sB10 = uB[2 * ks + 1][0], sB11 = uB[2 * ks + 1][1];
            uint32_t eB0 = (lg & 1) ? sB00 : sB10;
            uint32_t eB1 = (lg & 1) ? sB01 : sB11;
            uint32_t xB0 = (uint32_t)__shfl_xor((int)eB0, 16);
            uint32_t xB1 = (uint32_t)__shfl_xor((int)eB1, 16);
            union { uint32_t w4[4]; short8 s8; } puB;
            puB.w4[0] = (lg & 1) ? xB0 : sB00;
            puB.w4[1] = (lg & 1) ? xB1 : sB01;
            puB.w4[2] = (lg & 1) ? sB10 : xB0;
            puB.w4[3] = (lg & 1) ? sB11 : xB1;
            const int f = ks * 4 + ((lg & 1) << 1) + (lg >> 1);
            const int stv = f >> 3, fl = f & 7;
#pragma unroll
            for (int g = 0; g < 4; g++) {
                short8 vf = *(const short8*)&Vs[cur][stv][(g * 16 + li) * 64 + ((fl ^ (li & 7)) << 3)];
                accA[g] = __builtin_amdgcn_mfma_f32_16x16x32_bf16(vf, puA.s8, accA[g], 0, 0, 0);
                accB[g] = __builtin_amdgcn_mfma_f32_16x16x32_bf16(vf, puB.s8, accB[g], 0, 0, 0);
            }
        }
        __builtin_amdgcn_s_setprio(0);

        asm volatile("s_waitcnt vmcnt(0)" ::: "memory");   // prefetch landed
        __syncthreads();
        cur ^= 1;
        if (kt < S_ / 128 - 1) { mw4a = mwnA; mw4b = mwnB; }
    }

    // epilogue: deferred l reduction, then normalize + store (both sets)
    l_rA += __shfl_xor(l_rA, 16);
    l_rA += __shfl_xor(l_rA, 32);
    l_rB += __shfl_xor(l_rB, 16);
    l_rB += __shfl_xor(l_rB, 32);
    float invA = 1.f / l_rA, invB = 1.f / l_rB;
    short* orowA = &Op[(size_t)(b * S_ + qA) * D_ + h * 64];
    short* orowB = &Op[(size_t)(b * S_ + qB) * D_ + h * 64];
#pragma unroll
    for (int g = 0; g < 4; g++) {
        uint2 oa, ob;
        oa.x = cvt_pk_bf16(accA[g][0] * invA, accA[g][1] * invA);
        oa.y = cvt_pk_bf16(accA[g][2] * invA, accA[g][3] * invA);
        *(uint2*)&orowA[g * 16 + lg * 4] = oa;
        ob.x = cvt_pk_bf16(accB[g][0] * invB, accB[g][1] * invB);
        ob.y = cvt_pk_bf16(accB[g][2] * invB, accB[g][3] * invB);
        *(uint2*)&orowB[g * 16 + lg * 4] = ob;
    }
}

extern "C" void kernel_launch(void* const* d_in, const int* in_sizes, int n_in,
                              void* d_out, int out_size, void* d_ws, size_t ws_size,
                              hipStream_t stream) {
    const float* q  = (const float*)d_in[0];
    const float* k  = (const float*)d_in[1];
    const float* v  = (const float*)d_in[2];
    const int*   mk = (const int*)d_in[3];
    const float* wq = (const float*)d_in[4];
    const float* wk = (const float*)d_in[5];
    const float* wv = (const float*)d_in[6];
    const float* wo = (const float*)d_in[7];

    const size_t SZ = (size_t)B_ * S_ * D_;
    const size_t DD = (size_t)D_ * D_;
    const size_t NEED = (6 * SZ + 4 * DD) * 2 + (size_t)B_ * S_ * 64 * 4 + 256;
    if (ws_size < NEED) return;

    short* ws  = (short*)d_ws;
    short* qb  = ws;
    short* kb  = qb + SZ;
    short* vb  = kb + SZ;
    short* wqb = vb + SZ;
    short* wkb = wqb + DD;
    short* wvb = wkb + DD;
    short* wob = wvb + DD;
    short* Qp  = wob + DD;
    short* Kp  = Qp + SZ;
    short* Vtr = Kp + SZ;       // V projection written DIRECTLY in V^T layout (fused)
    uint32_t* mp = (uint32_t*)(Vtr + SZ);
    float* lutg = (float*)(mp + (size_t)B_ * S_ * 64);
    short* Opx = kb;            // alias: kb dead after K-GEMM

    dim3 blk(256);
    prep<<<dim3(16384), blk, 0, stream>>>(q, k, v, wq, wk, wv, wo, mk,
                                          qb, kb, vb, wqb, wkb, wvb, wob, mp, lutg);

    gemm3_nt<<<dim3(8, 32, 3), blk, 0, stream>>>(qb, wqb, Qp, kb, wkb, Kp, vb, wvb, Vtr);

    attn_kernel<<<dim3(16, 32), dim3(256), 0, stream>>>(Qp, Kp, Vtr, mp, lutg, Opx);

    gemm_out<<<dim3(8, 64), blk, 0, stream>>>(Opx, wob, (float*)d_out);
}

// Round 18
// 149.214 us; speedup vs baseline: 1.0623x; 1.0623x over previous
//
#include <hip/hip_runtime.h>
#include <stdint.h>

#define B_ 2
#define S_ 2048
#define D_ 1024
#define H_ 16
#define DK_ 64

typedef __attribute__((ext_vector_type(8))) short short8;   // 8 x bf16 (raw bits)
typedef __attribute__((ext_vector_type(4))) float f32x4;

__device__ __forceinline__ short f2bf(float f) {
    uint32_t u = __float_as_uint(f);
    return (short)((u + 0x7FFFu + ((u >> 16) & 1u)) >> 16);
}

__device__ __forceinline__ float fexp2(float x) {
    float r;
    asm("v_exp_f32 %0, %1" : "=v"(r) : "v"(x));
    return r;
}

__device__ __forceinline__ uint32_t cvt_pk_bf16(float lo, float hi) {
    uint32_t r;
    asm("v_cvt_pk_bf16_f32 %0, %1, %2" : "=v"(r) : "v"(lo), "v"(hi));
    return r;
}

#define GLOAD16(gptr, lptr)                                                      \
    __builtin_amdgcn_global_load_lds(                                            \
        (const __attribute__((address_space(1))) void*)(gptr),                   \
        (__attribute__((address_space(3))) void*)(lptr), 16, 0, 0)

// ---------------- fused prep: casts + mask pack + LUT ----------------
__global__ __launch_bounds__(256) void prep(const float* __restrict__ q,
                                            const float* __restrict__ k,
                                            const float* __restrict__ v,
                                            const float* __restrict__ wq,
                                            const float* __restrict__ wk,
                                            const float* __restrict__ wv,
                                            const float* __restrict__ wo,
                                            const int* __restrict__ mask,
                                            short* __restrict__ qb, short* __restrict__ kb,
                                            short* __restrict__ vb,
                                            short* __restrict__ wqb, short* __restrict__ wkb,
                                            short* __restrict__ wvb, short* __restrict__ wob,
                                            uint32_t* __restrict__ packed,
                                            float* __restrict__ lut) {
    int bid = blockIdx.x;
    int tid = threadIdx.x;
    if (bid < 8192) {
        const float* in;
        short* out;
        int i;
        if (bid < 6144) {
            int sel = bid >> 11;
            i = (bid & 2047) * 256 + tid;
            in = (sel == 0) ? q : (sel == 1) ? k : v;
            out = (sel == 0) ? qb : (sel == 1) ? kb : vb;
        } else {
            int idx = bid - 6144;
            int sel = idx >> 9;
            i = (idx & 511) * 256 + tid;
            in = (sel == 0) ? wq : (sel == 1) ? wk : (sel == 2) ? wv : wo;
            out = (sel == 0) ? wqb : (sel == 1) ? wkb : (sel == 2) ? wvb : wob;
            if (idx == 0 && tid < 64) {
                int e = tid >> 2, r = tid & 3;
                lut[tid] = ((e >> r) & 1) ? 0.0f : -8.0e9f;   // raw-score bias (x0.125 => -1e9)
            }
        }
        const float4* p = ((const float4*)in) + (size_t)i * 2;
        float4 x = p[0], y = p[1];
        short8 o;
        o[0] = f2bf(x.x); o[1] = f2bf(x.y); o[2] = f2bf(x.z); o[3] = f2bf(x.w);
        o[4] = f2bf(y.x); o[5] = f2bf(y.y); o[6] = f2bf(y.z); o[7] = f2bf(y.w);
        *(((short8*)out) + i) = o;
    } else {
        size_t t = (size_t)(bid - 8192) * 256 + tid;   // covers 4 mask elems
        int4 m = ((const int4*)mask)[t];
        uint32_t nib = (m.x != 0 ? 1u : 0u) | (m.y != 0 ? 2u : 0u) |
                       (m.z != 0 ? 4u : 0u) | (m.w != 0 ? 8u : 0u);
        int lane = tid & 63;
        uint32_t vv = nib << ((lane & 7) * 4);
        vv |= __shfl_xor(vv, 1);
        vv |= __shfl_xor(vv, 2);
        vv |= __shfl_xor(vv, 4);
        if ((lane & 7) == 0) packed[t >> 3] = vv;
    }
}

// ---------------- GEMM body: C[M,N] = A * W^T, 128x128 tile, BK=32 (R9 proven) ----------------
// grid must be (8, 32[, z]); XCD-chunked swizzle: each XCD gets 4 M-rows x 8 N-cols.
#define GEMM_BODY(A, W, C, F32OUT, Mv, Nv, Kv)                                              \
    __shared__ short As[128 * 32];                                                          \
    __shared__ short Bs[128 * 32];                                                          \
    const int tid = threadIdx.x;                                                            \
    const int lane = tid & 63;                                                              \
    const int w = tid >> 6;                                                                 \
    const int wm = w >> 1, wn = w & 1;                                                      \
    const int l_ = blockIdx.x + (blockIdx.y << 3);                                          \
    const int xcd_ = l_ & 7, ii_ = l_ >> 3;                                                 \
    const int mBase = ((xcd_ << 2) + (ii_ >> 3)) * 128;                                     \
    const int nBase = (ii_ & 7) * 128;                                                      \
    f32x4 acc[4][4];                                                                        \
    _Pragma("unroll") for (int i = 0; i < 4; i++)                                           \
        _Pragma("unroll") for (int j = 0; j < 4; j++) acc[i][j] = (f32x4)0.f;               \
    const int srow = lane >> 2;                                                             \
    const int sslot = lane & 3;                                                             \
    for (int k0 = 0; k0 < Kv; k0 += 32) {                                                   \
        _Pragma("unroll") for (int i = 0; i < 2; ++i) {                                     \
            int seg = w * 2 + i;                                                            \
            int row = seg * 16 + srow;                                                      \
            const short* ga = A + (size_t)(mBase + row) * Kv + k0 + sslot * 8;              \
            GLOAD16(ga, (char*)As + seg * 1024);                                            \
            const short* gb = W + (size_t)(nBase + row) * Kv + k0 + sslot * 8;              \
            GLOAD16(gb, (char*)Bs + seg * 1024);                                            \
        }                                                                                   \
        asm volatile("s_waitcnt vmcnt(0)" ::: "memory");                                    \
        __syncthreads();                                                                    \
        short8 af[4], bfv[4];                                                               \
        _Pragma("unroll") for (int mi = 0; mi < 4; mi++)                                    \
            af[mi] = *(const short8*)&As[(wm * 64 + mi * 16 + (lane & 15)) * 32 + (lane >> 4) * 8]; \
        _Pragma("unroll") for (int ni = 0; ni < 4; ni++)                                    \
            bfv[ni] = *(const short8*)&Bs[(wn * 64 + ni * 16 + (lane & 15)) * 32 + (lane >> 4) * 8]; \
        _Pragma("unroll") for (int mi = 0; mi < 4; mi++)                                    \
            _Pragma("unroll") for (int ni = 0; ni < 4; ni++)                                \
                acc[mi][ni] = __builtin_amdgcn_mfma_f32_16x16x32_bf16(af[mi], bfv[ni], acc[mi][ni], 0, 0, 0); \
        __syncthreads();                                                                    \
    }                                                                                       \
    _Pragma("unroll") for (int mi = 0; mi < 4; mi++)                                        \
        _Pragma("unroll") for (int ni = 0; ni < 4; ni++)                                    \
            _Pragma("unroll") for (int r = 0; r < 4; r++) {                                 \
                int row = mBase + wm * 64 + mi * 16 + (lane >> 4) * 4 + r;                  \
                int col = nBase + wn * 64 + ni * 16 + (lane & 15);                          \
                float v = acc[mi][ni][r];                                                   \
                if (F32OUT) ((float*)C)[(size_t)row * Nv + col] = v;                        \
                else        ((short*)C)[(size_t)row * Nv + col] = f2bf(v);                  \
            }

__global__ __launch_bounds__(256) void gemm3_nt(const short* __restrict__ A0, const short* __restrict__ W0, short* __restrict__ C0,
                                                const short* __restrict__ A1, const short* __restrict__ W1, short* __restrict__ C1,
                                                const short* __restrict__ A2, const short* __restrict__ W2, short* __restrict__ C2) {
    const int z = blockIdx.z;
    const short* A = (z == 0) ? A0 : (z == 1) ? A1 : A2;
    const short* W = (z == 0) ? W0 : (z == 1) ? W1 : W2;
    short* C = (z == 0) ? C0 : (z == 1) ? C1 : C2;
    GEMM_BODY(A, W, C, 0, (B_ * S_), D_, D_)
}

// ---------------- gemm_out: 64x128 tile, grid (8,64) = 512 blocks = 2 blk/CU ----------------
// wave w: wm = w>>1 (32-row half), wn = w&1 (64-col half). A: 1 GLOAD/thread, B: 2.
__global__ __launch_bounds__(256) void gemm_out(const short* __restrict__ A,
                                                const short* __restrict__ W,
                                                float* __restrict__ C) {
    __shared__ short As[64 * 32];     // 4 KB
    __shared__ short Bs[128 * 32];    // 8 KB
    const int tid = threadIdx.x;
    const int lane = tid & 63;
    const int w = tid >> 6;
    const int wm = w >> 1, wn = w & 1;
    const int li = lane & 15, lg = lane >> 4;
    const int l_ = blockIdx.x + (blockIdx.y << 3);
    const int xcd_ = l_ & 7, ii_ = l_ >> 3;           // ii_ in [0,64)
    const int mBase = ((xcd_ << 3) + (ii_ >> 3)) * 64;  // 64 m-tiles of 64 rows
    const int nBase = (ii_ & 7) * 128;
    const int Kv = D_, Nv = D_;
    f32x4 acc[2][4];
#pragma unroll
    for (int i = 0; i < 2; i++)
#pragma unroll
        for (int j = 0; j < 4; j++) acc[i][j] = (f32x4)0.f;
    const int srow = lane >> 2;       // 0..15 within 16-row segment
    const int sslot = lane & 3;
    for (int k0 = 0; k0 < Kv; k0 += 32) {
        {   // A: 4 segments, one per wave (64 rows total)
            int row = w * 16 + srow;
            const short* ga = A + (size_t)(mBase + row) * Kv + k0 + sslot * 8;
            GLOAD16(ga, (char*)As + w * 1024);
        }
#pragma unroll
        for (int i = 0; i < 2; ++i) {   // B: 8 segments, two per wave
            int seg = w * 2 + i;
            int row = seg * 16 + srow;
            const short* gb = W + (size_t)(nBase + row) * Kv + k0 + sslot * 8;
            GLOAD16(gb, (char*)Bs + seg * 1024);
        }
        asm volatile("s_waitcnt vmcnt(0)" ::: "memory");
        __syncthreads();
        short8 af[2], bfv[4];
#pragma unroll
        for (int mi = 0; mi < 2; mi++)
            af[mi] = *(const short8*)&As[(wm * 32 + mi * 16 + li) * 32 + lg * 8];
#pragma unroll
        for (int ni = 0; ni < 4; ni++)
            bfv[ni] = *(const short8*)&Bs[(wn * 64 + ni * 16 + li) * 32 + lg * 8];
#pragma unroll
        for (int mi = 0; mi < 2; mi++)
#pragma unroll
            for (int ni = 0; ni < 4; ni++)
                acc[mi][ni] = __builtin_amdgcn_mfma_f32_16x16x32_bf16(af[mi], bfv[ni], acc[mi][ni], 0, 0, 0);
        __syncthreads();
    }
#pragma unroll
    for (int mi = 0; mi < 2; mi++)
#pragma unroll
        for (int ni = 0; ni < 4; ni++)
#pragma unroll
            for (int r = 0; r < 4; r++) {
                int row = mBase + wm * 32 + mi * 16 + lg * 4 + r;
                int col = nBase + wn * 64 + ni * 16 + li;
                C[(size_t)row * Nv + col] = acc[mi][ni][r];
            }
}

// ---------------- V transpose: Vp[b,s,h*64+dk] -> Vt[(b*H+h)*64+dk][s] ----------------
__global__ __launch_bounds__(256) void transpose_v(const short* __restrict__ Vp,
                                                   short* __restrict__ Vt) {
    __shared__ short t[64 * 72];
    int bid = blockIdx.x;
    int bh = bid >> 5;
    int st = bid & 31;
    int b = bh >> 4, h = bh & 15;
    int sBase = st * 64;
    int tid = threadIdx.x;
#pragma unroll
    for (int i = 0; i < 2; i++) {
        int ci = i * 256 + tid;
        int sr = ci >> 3, sl = ci & 7;
        short8 v = *(const short8*)&Vp[(size_t)(b * S_ + sBase + sr) * D_ + h * 64 + sl * 8];
#pragma unroll
        for (int j = 0; j < 8; j++) t[(sl * 8 + j) * 72 + sr] = v[j];
    }
    __syncthreads();
#pragma unroll
    for (int i = 0; i < 2; i++) {
        int ci = i * 256 + tid;
        int dk = ci >> 3, sl = ci & 7;
        short8 o = *(const short8*)&t[dk * 72 + sl * 8];
        *(short8*)&Vt[(size_t)((b * H_ + h) * 64 + dk) * S_ + sBase + sl * 8] = o;
    }
}

// ---------------- flash attention: QBLK=128, 4 waves x 32 q-rows (dual q-set), KVBLK=128 ----------------
// R11-proven body: defer-max + deferred l-sum. grid (16,32) swizzled, 256 threads.
__global__ __launch_bounds__(256) void attn_kernel(const short* __restrict__ Qp,
                                                   const short* __restrict__ Kp,
                                                   const short* __restrict__ Vt,
                                                   const uint32_t* __restrict__ mp,
                                                   const float* __restrict__ lutg,
                                                   short* __restrict__ Op) {
    __shared__ short Ks[2][2][64 * 64];   // [dbuf][sub-tile][row*64+col] = 32 KB
    __shared__ short Vs[2][2][64 * 64];   // 32 KB
    // XCD-chunked: each XCD owns 4 consecutive bh
    const int l_ = blockIdx.x + (blockIdx.y << 4);
    const int bh = ((l_ & 7) << 2) + (l_ >> 7);
    const int qt = (l_ >> 3) & 15;
    const int b = bh >> 4, h = bh & 15;
    const int qBase = qt * 128;
    const int tid = threadIdx.x, lane = tid & 63, w = tid >> 6;
    const int lg = lane >> 4;
    const int li = lane & 15;
    const float c1 = 0.18033688011112042f;   // 0.125 * log2(e)

    const int qA = qBase + w * 32 + li;       // set A q-row
    const int qB = qA + 16;                   // set B q-row

    short8 qfA[2], qfB[2];
#pragma unroll
    for (int ks = 0; ks < 2; ks++) {
        qfA[ks] = *(const short8*)&Qp[(size_t)(b * S_ + qA) * D_ + h * 64 + lg * 8 + ks * 32];
        qfB[ks] = *(const short8*)&Qp[(size_t)(b * S_ + qB) * D_ + h * 64 + lg * 8 + ks * 32];
    }

    // staging (256 threads): per 8KB subtile, two lines (rows r0, r0+32)
    const int r0 = tid >> 3, sl = tid & 7;
    const int gs = sl ^ (r0 & 7);
    const short* kgb = Kp + ((size_t)(b * S_) + r0) * D_ + h * 64 + gs * 8;   // + krow*D
    const short* vgb = Vt + ((size_t)bh * 64 + r0) * S_ + gs * 8;             // + kcol
    const uint32_t* mrowA = mp + ((size_t)(b * S_) + qA) * 64;
    const uint32_t* mrowB = mp + ((size_t)(b * S_) + qB) * 64;
    char* ldsK = (char*)&Ks[0][0][0];
    char* ldsV = (char*)&Vs[0][0][0];
    const int woff = w * 1024;

    // prologue: stage pair 0 into buffer 0
#pragma unroll
    for (int st = 0; st < 2; st++) {
        GLOAD16(kgb + (size_t)(st * 64) * D_, ldsK + st * 8192 + woff);
        GLOAD16(kgb + (size_t)(st * 64 + 32) * D_, ldsK + st * 8192 + 4096 + woff);
        GLOAD16(vgb + st * 64, ldsV + st * 8192 + woff);
        GLOAD16(vgb + st * 64 + (size_t)32 * S_, ldsV + st * 8192 + 4096 + woff);
    }
    uint4 mw4a = *(const uint4*)mrowA;
    uint4 mw4b = *(const uint4*)mrowB;
    asm volatile("s_waitcnt vmcnt(0)" ::: "memory");
    __syncthreads();

    float m_rA = -1e30f, l_rA = 0.f, m_rB = -1e30f, l_rB = 0.f;
    f32x4 accA[4], accB[4];
#pragma unroll
    for (int g = 0; g < 4; g++) { accA[g] = (f32x4)0.f; accB[g] = (f32x4)0.f; }

    int cur = 0;

    for (int kt = 0; kt < S_ / 128; ++kt) {
        // mask bias LUT loads FIRST
        uint32_t mwaA[4] = {mw4a.x, mw4a.y, mw4a.z, mw4a.w};
        uint32_t mwaB[4] = {mw4b.x, mw4b.y, mw4b.z, mw4b.w};
        f32x4 mskA[8], mskB[8];
#pragma unroll
        for (int nt = 0; nt < 8; nt++) {
            uint32_t sh = ((nt & 1) << 4) + (lg << 2);
            mskA[nt] = *(const f32x4*)&lutg[((mwaA[nt >> 1] >> sh) & 0xFu) * 4];
            mskB[nt] = *(const f32x4*)&lutg[((mwaB[nt >> 1] >> sh) & 0xFu) * 4];
        }

        uint4 mwnA, mwnB;
        if (kt < S_ / 128 - 1) {   // async prefetch of next 128-tile
            const int boff = (cur ^ 1) * 16384 + woff;
#pragma unroll
            for (int st = 0; st < 2; st++) {
                const size_t kr = (size_t)((kt + 1) * 128 + st * 64);
                GLOAD16(kgb + kr * D_, ldsK + boff + st * 8192);
                GLOAD16(kgb + (kr + 32) * D_, ldsK + boff + st * 8192 + 4096);
                GLOAD16(vgb + kr, ldsV + boff + st * 8192);
                GLOAD16(vgb + kr + (size_t)32 * S_, ldsV + boff + st * 8192 + 4096);
            }
            mwnA = *(const uint4*)&mrowA[(kt + 1) * 4];
            mwnB = *(const uint4*)&mrowB[(kt + 1) * 4];
        }

        // S^T = K Q^T + mask_bias: each kf read feeds BOTH q-sets
        f32x4 scA[8], scB[8];
        __builtin_amdgcn_s_setprio(1);
#pragma unroll
        for (int st = 0; st < 2; st++)
#pragma unroll
            for (int ntl = 0; ntl < 4; ntl++) {
                f32x4 cA = mskA[st * 4 + ntl];
                f32x4 cB = mskB[st * 4 + ntl];
#pragma unroll
                for (int ks = 0; ks < 2; ks++) {
                    short8 kf = *(const short8*)&Ks[cur][st][(ntl * 16 + li) * 64 + (((lg + ks * 4) ^ (li & 7)) << 3)];
                    cA = __builtin_amdgcn_mfma_f32_16x16x32_bf16(kf, qfA[ks], cA, 0, 0, 0);
                    cB = __builtin_amdgcn_mfma_f32_16x16x32_bf16(kf, qfB[ks], cB, 0, 0, 0);
                }
                scA[st * 4 + ntl] = cA;
                scB[st * 4 + ntl] = cB;
            }
        __builtin_amdgcn_s_setprio(0);

        // row max per set (balanced trees + 2 shfl each)
        float a0 = fmaxf(fmaxf(scA[0][0], scA[0][1]), fmaxf(scA[0][2], scA[0][3]));
        float a1 = fmaxf(fmaxf(scA[1][0], scA[1][1]), fmaxf(scA[1][2], scA[1][3]));
        float a2 = fmaxf(fmaxf(scA[2][0], scA[2][1]), fmaxf(scA[2][2], scA[2][3]));
        float a3 = fmaxf(fmaxf(scA[3][0], scA[3][1]), fmaxf(scA[3][2], scA[3][3]));
        float a4 = fmaxf(fmaxf(scA[4][0], scA[4][1]), fmaxf(scA[4][2], scA[4][3]));
        float a5 = fmaxf(fmaxf(scA[5][0], scA[5][1]), fmaxf(scA[5][2], scA[5][3]));
        float a6 = fmaxf(fmaxf(scA[6][0], scA[6][1]), fmaxf(scA[6][2], scA[6][3]));
        float a7 = fmaxf(fmaxf(scA[7][0], scA[7][1]), fmaxf(scA[7][2], scA[7][3]));
        float tmA = fmaxf(fmaxf(fmaxf(a0, a1), fmaxf(a2, a3)),
                          fmaxf(fmaxf(a4, a5), fmaxf(a6, a7)));
        tmA = fmaxf(tmA, __shfl_xor(tmA, 16));
        tmA = fmaxf(tmA, __shfl_xor(tmA, 32));
        float b0 = fmaxf(fmaxf(scB[0][0], scB[0][1]), fmaxf(scB[0][2], scB[0][3]));
        float b1 = fmaxf(fmaxf(scB[1][0], scB[1][1]), fmaxf(scB[1][2], scB[1][3]));
        float b2 = fmaxf(fmaxf(scB[2][0], scB[2][1]), fmaxf(scB[2][2], scB[2][3]));
        float b3 = fmaxf(fmaxf(scB[3][0], scB[3][1]), fmaxf(scB[3][2], scB[3][3]));
        float b4 = fmaxf(fmaxf(scB[4][0], scB[4][1]), fmaxf(scB[4][2], scB[4][3]));
        float b5 = fmaxf(fmaxf(scB[5][0], scB[5][1]), fmaxf(scB[5][2], scB[5][3]));
        float b6 = fmaxf(fmaxf(scB[6][0], scB[6][1]), fmaxf(scB[6][2], scB[6][3]));
        float b7 = fmaxf(fmaxf(scB[7][0], scB[7][1]), fmaxf(scB[7][2], scB[7][3]));
        float tmB = fmaxf(fmaxf(fmaxf(b0, b1), fmaxf(b2, b3)),
                          fmaxf(fmaxf(b4, b5), fmaxf(b6, b7)));
        tmB = fmaxf(tmB, __shfl_xor(tmB, 16));
        tmB = fmaxf(tmB, __shfl_xor(tmB, 32));

        // combined defer-max (rescale both sets when either grows)
        if (__any(((tmA - m_rA) * c1 > 10.0f) || ((tmB - m_rB) * c1 > 10.0f))) {
            float mnA = fmaxf(m_rA, tmA);
            float alA = fexp2((m_rA - mnA) * c1);
            m_rA = mnA; l_rA *= alA;
            float mnB = fmaxf(m_rB, tmB);
            float alB = fexp2((m_rB - mnB) * c1);
            m_rB = mnB; l_rB *= alB;
#pragma unroll
            for (int g = 0; g < 4; g++) { accA[g] *= alA; accB[g] *= alB; }
        }
        float mcA = m_rA * c1, mcB = m_rB * c1;

        // p = exp2(s*c1 - mc); pack bf16 pairs (per set); l-sum kept per-lane (deferred reduce)
        uint32_t uA[8][2], uB[8][2];
        float lsA = 0.f, lsB = 0.f;
#pragma unroll
        for (int nt = 0; nt < 8; nt++) {
            float e0 = fexp2(__builtin_fmaf(scA[nt][0], c1, -mcA));
            float e1 = fexp2(__builtin_fmaf(scA[nt][1], c1, -mcA));
            float e2 = fexp2(__builtin_fmaf(scA[nt][2], c1, -mcA));
            float e3 = fexp2(__builtin_fmaf(scA[nt][3], c1, -mcA));
            lsA += (e0 + e1) + (e2 + e3);
            uA[nt][0] = cvt_pk_bf16(e0, e1);
            uA[nt][1] = cvt_pk_bf16(e2, e3);
            float f0 = fexp2(__builtin_fmaf(scB[nt][0], c1, -mcB));
            float f1 = fexp2(__builtin_fmaf(scB[nt][1], c1, -mcB));
            float f2 = fexp2(__builtin_fmaf(scB[nt][2], c1, -mcB));
            float f3 = fexp2(__builtin_fmaf(scB[nt][3], c1, -mcB));
            lsB += (f0 + f1) + (f2 + f3);
            uB[nt][0] = cvt_pk_bf16(f0, f1);
            uB[nt][1] = cvt_pk_bf16(f2, f3);
        }
        l_rA += lsA;    // per-lane partial; cross-lane reduce deferred to epilogue
        l_rB += lsB;

        // O^T += V^T P^T; each vf read feeds BOTH q-sets; P redistribution via xor-16
        __builtin_amdgcn_s_setprio(1);
#pragma unroll
        for (int ks = 0; ks < 4; ks++) {
            const uint32_t sA00 = uA[2 * ks][0], sA01 = uA[2 * ks][1];
            const uint32_t sA10 = uA[2 * ks + 1][0], sA11 = uA[2 * ks + 1][1];
            uint32_t eA0 = (lg & 1) ? sA00 : sA10;
            uint32_t eA1 = (lg & 1) ? sA01 : sA11;
            uint32_t xA0 = (uint32_t)__shfl_xor((int)eA0, 16);
            uint32_t xA1 = (uint32_t)__shfl_xor((int)eA1, 16);
            union { uint32_t w4[4]; short8 s8; } puA;
            puA.w4[0] = (lg & 1) ? xA0 : sA00;
            puA.w4[1] = (lg & 1) ? xA1 : sA01;
            puA.w4[2] = (lg & 1) ? sA10 : xA0;
            puA.w4[3] = (lg & 1) ? sA11 : xA1;
            const uint32_t sB00 = uB[2 * ks][0], sB01 = uB[2 * ks][1];
            const uint32_t sB10 = uB[2 * ks + 1][0], sB11 = uB[2 * ks + 1][1];
            uint32_t eB0 = (lg & 1) ? sB00 : sB10;
            uint32_t eB1 = (lg & 1) ? sB01 : sB11;
            uint32_t xB0 = (uint32_t)__shfl_xor((int)eB0, 16);
            uint32_t xB1 = (uint32_t)__shfl_xor((int)eB1, 16);
            union { uint32_t w4[4]; short8 s8; } puB;
            puB.w4[0] = (lg & 1) ? xB0 : sB00;
            puB.w4[1] = (lg & 1) ? xB1 : sB01;
            puB.w4[2] = (lg & 1) ? sB10 : xB0;
            puB.w4[3] = (lg & 1) ? sB11 : xB1;
            const int f = ks * 4 + ((lg & 1) << 1) + (lg >> 1);
            const int stv = f >> 3, fl = f & 7;
#pragma unroll
            for (int g = 0; g < 4; g++) {
                short8 vf = *(const short8*)&Vs[cur][stv][(g * 16 + li) * 64 + ((fl ^ (li & 7)) << 3)];
                accA[g] = __builtin_amdgcn_mfma_f32_16x16x32_bf16(vf, puA.s8, accA[g], 0, 0, 0);
                accB[g] = __builtin_amdgcn_mfma_f32_16x16x32_bf16(vf, puB.s8, accB[g], 0, 0, 0);
            }
        }
        __builtin_amdgcn_s_setprio(0);

        asm volatile("s_waitcnt vmcnt(0)" ::: "memory");   // prefetch landed
        __syncthreads();
        cur ^= 1;
        if (kt < S_ / 128 - 1) { mw4a = mwnA; mw4b = mwnB; }
    }

    // epilogue: deferred l reduction, then normalize + store (both sets)
    l_rA += __shfl_xor(l_rA, 16);
    l_rA += __shfl_xor(l_rA, 32);
    l_rB += __shfl_xor(l_rB, 16);
    l_rB += __shfl_xor(l_rB, 32);
    float invA = 1.f / l_rA, invB = 1.f / l_rB;
    short* orowA = &Op[(size_t)(b * S_ + qA) * D_ + h * 64];
    short* orowB = &Op[(size_t)(b * S_ + qB) * D_ + h * 64];
#pragma unroll
    for (int g = 0; g < 4; g++) {
        uint2 oa, ob;
        oa.x = cvt_pk_bf16(accA[g][0] * invA, accA[g][1] * invA);
        oa.y = cvt_pk_bf16(accA[g][2] * invA, accA[g][3] * invA);
        *(uint2*)&orowA[g * 16 + lg * 4] = oa;
        ob.x = cvt_pk_bf16(accB[g][0] * invB, accB[g][1] * invB);
        ob.y = cvt_pk_bf16(accB[g][2] * invB, accB[g][3] * invB);
        *(uint2*)&orowB[g * 16 + lg * 4] = ob;
    }
}

extern "C" void kernel_launch(void* const* d_in, const int* in_sizes, int n_in,
                              void* d_out, int out_size, void* d_ws, size_t ws_size,
                              hipStream_t stream) {
    const float* q  = (const float*)d_in[0];
    const float* k  = (const float*)d_in[1];
    const float* v  = (const float*)d_in[2];
    const int*   mk = (const int*)d_in[3];
    const float* wq = (const float*)d_in[4];
    const float* wk = (const float*)d_in[5];
    const float* wv = (const float*)d_in[6];
    const float* wo = (const float*)d_in[7];

    const size_t SZ = (size_t)B_ * S_ * D_;
    const size_t DD = (size_t)D_ * D_;
    const size_t NEED = (6 * SZ + 4 * DD) * 2 + (size_t)B_ * S_ * 64 * 4 + 256;
    if (ws_size < NEED) return;

    short* ws  = (short*)d_ws;
    short* qb  = ws;
    short* kb  = qb + SZ;
    short* vb  = kb + SZ;
    short* wqb = vb + SZ;
    short* wkb = wqb + DD;
    short* wvb = wkb + DD;
    short* wob = wvb + DD;
    short* Qp  = wob + DD;
    short* Kp  = Qp + SZ;
    short* Vp  = Kp + SZ;
    uint32_t* mp = (uint32_t*)(Vp + SZ);
    float* lutg = (float*)(mp + (size_t)B_ * S_ * 64);
    short* Vtr = qb;            // alias: qb dead after Q-GEMM
    short* Opx = kb;            // alias: kb dead after K-GEMM

    dim3 blk(256);
    prep<<<dim3(16384), blk, 0, stream>>>(q, k, v, wq, wk, wv, wo, mk,
                                          qb, kb, vb, wqb, wkb, wvb, wob, mp, lutg);

    gemm3_nt<<<dim3(8, 32, 3), blk, 0, stream>>>(qb, wqb, Qp, kb, wkb, Kp, vb, wvb, Vp);

    transpose_v<<<dim3(B_ * H_ * (S_ / 64)), blk, 0, stream>>>(Vp, Vtr);

    attn_kernel<<<dim3(16, 32), dim3(256), 0, stream>>>(Qp, Kp, Vtr, mp, lutg, Opx);

    gemm_out<<<dim3(8, 64), blk, 0, stream>>>(Opx, wob, (float*)d_out);
}